// Round 3
// baseline (82712.006 us; speedup 1.0000x reference)
//
#include <hip/hip_runtime.h>
#include <math.h>

#define L_SEQ 8192
#define I_DIM 256
#define H_DIM 2048
#define NWG0  32          // layer-0: 32 WGs x 64 rows
#define NWG1  64          // layer-1: 64 WGs x 32 rows
#define NWG   (NWG0 + NWG1)
#define TPB   1024
#define NSTEP (L_SEQ + 1)

// ws layout (bytes): [0] runctr | [256..640) barrier slots | [1024) h0 ring 8*2048 f32
//                    | [66560) h1 ring 8*2048 f32
//
// Self-tagged publication (no per-step barrier): stored value v = h + 4 + 8*tag,
// tag = (step>>3)&1, ring depth 8. Valid iff |v - center| <= 1 (h = tanh in [-1,1]).
// 0xAA poison (-3e-13) and the 0.0f invalidation marker fall outside both windows,
// so stale/poisoned slots can never false-match. Each run: invalidate own slots +
// write h_0, one start barrier, then pure data-flow polling. Run-ahead is bounded
// by ring depth via a 1-word throttle (layer-0 waits for h1_{s-4}; margin 3 vs
// the depth-8 ring, see derivation in round-3 notes).

__device__ __forceinline__ void cstore1(float* p, float v) {
  asm volatile("global_store_dword %0, %1, off sc0 sc1" :: "v"(p), "v"(v) : "memory");
}
__device__ __forceinline__ float cload1(const float* p) {
  float v;
  asm volatile("global_load_dword %0, %1, off sc0 sc1\n\ts_waitcnt vmcnt(0)"
               : "=v"(v) : "v"(p) : "memory");
  return v;
}
__device__ __forceinline__ float4 cload4(const float* p) {
  float4 v;
  asm volatile("global_load_dwordx4 %0, %1, off sc0 sc1\n\ts_waitcnt vmcnt(0)"
               : "=v"(v) : "v"(p) : "memory");
  return v;
}
// Weight load: opaque to LLVM -> result CANNOT be rematerialized, forcing VGPR residency.
__device__ __forceinline__ float4 ld4(const float* p) {
  float4 v;
  asm volatile("global_load_dwordx4 %0, %1, off\n\ts_waitcnt vmcnt(0)"
               : "=v"(v) : "v"(p) : "memory");
  return v;
}
__device__ __forceinline__ float dot4(float4 a, float4 b) {
  return a.x * b.x + a.y * b.y + a.z * b.z + a.w * b.w;
}
// Poll a 4-float tagged chunk until valid; return decoded h values.
__device__ __forceinline__ float4 poll4(const float* p, float ctr) {
  for (;;) {
    float4 v = cload4(p);
    if (__builtin_fabsf(v.x - ctr) <= 1.f && __builtin_fabsf(v.y - ctr) <= 1.f &&
        __builtin_fabsf(v.z - ctr) <= 1.f && __builtin_fabsf(v.w - ctr) <= 1.f)
      return make_float4(v.x - ctr, v.y - ctr, v.z - ctr, v.w - ctr);
  }
}
__device__ __forceinline__ float tagctr(int step) {
  return 4.f + 8.f * (float)((step >> 3) & 1);
}

__device__ __forceinline__ void start_barrier(unsigned* slots, int wg, int tid, unsigned value) {
  __syncthreads();  // drains vmcnt(0): invalidation stores are at the coherence point
  if (tid == 0)
    __hip_atomic_store(&slots[wg], value, __ATOMIC_RELAXED, __HIP_MEMORY_SCOPE_AGENT);
  if (tid < NWG) {
    while ((int)(__hip_atomic_load(&slots[tid], __ATOMIC_RELAXED, __HIP_MEMORY_SCOPE_AGENT) - value) < 0)
      __builtin_amdgcn_s_sleep(1);
  }
  __syncthreads();
}

__global__ __launch_bounds__(TPB, 1)
void rnn2_dataflow(const float* __restrict__ x,
                   const float* __restrict__ Wih0, const float* __restrict__ Whh0,
                   const float* __restrict__ bih0, const float* __restrict__ bhh0,
                   const float* __restrict__ Wih1, const float* __restrict__ Whh1,
                   const float* __restrict__ bih1, const float* __restrict__ bhh1,
                   const float* __restrict__ Wfc,  const float* __restrict__ bfc,
                   float* __restrict__ out,
                   unsigned* __restrict__ runctr, unsigned* __restrict__ slots,
                   float* __restrict__ h0s, float* __restrict__ h1s)
{
  const int wg  = blockIdx.x;
  const int tid = threadIdx.x;
  __shared__ float4 lds4[2][1024];

  const unsigned runbase = __hip_atomic_load(runctr, __ATOMIC_RELAXED, __HIP_MEMORY_SCOPE_AGENT);

  if (wg < NWG0) {
    // ---------------- layer 0: 64 rows/WG, 16 threads/row ----------------
    const int cg  = tid & 15;
    const int row = wg * 64 + (tid >> 4);
    float4 wihr[4], whhr[32];
    {
      const float* wr = Wih0 + (size_t)row * I_DIM + (cg << 2);
      #pragma unroll
      for (int k = 0; k < 4; ++k) wihr[k] = ld4(wr + (k << 6));
      const float* wr2 = Whh0 + (size_t)row * H_DIM + (cg << 2);
      #pragma unroll
      for (int k = 0; k < 32; ++k) whhr[k] = ld4(wr2 + (k << 6));
    }
    const float bias = bih0[row] + bhh0[row];

    // init: h0_0 = 0 (tagged, slot 0), invalidate slots 1..7 for owned rows
    if (tid < 64) cstore1(&h0s[wg * 64 + tid], 4.0f);
    if (tid < 448) {
      int sl = 1 + (tid >> 6);
      cstore1(&h0s[sl * H_DIM + wg * 64 + (tid & 63)], 0.0f);
    }
    start_barrier(slots, wg, tid, runbase + 1);

    for (int s = 1; s <= L_SEQ; ++s) {
      const int p = s & 1;
      if (tid < 512) {
        lds4[p][64 + tid] = poll4(h0s + ((s - 1) & 7) * H_DIM + tid * 4, tagctr(s - 1));
      } else if (tid < 576) {
        lds4[p][tid - 512] = ((const float4*)(x + (size_t)(s - 1) * I_DIM))[tid - 512];
      } else if (tid == 1023 && s >= 5) {
        // throttle: don't overwrite ring slot s&7 until layer-1 has provably consumed it
        const float* tp = h1s + ((s - 4) & 7) * H_DIM + (wg << 6);
        const float c = tagctr(s - 4);
        while (__builtin_fabsf(cload1(tp) - c) > 1.f) {}
      }
      __syncthreads();
      float acc = 0.f;
      #pragma unroll
      for (int k = 0; k < 4; ++k)  acc += dot4(wihr[k], lds4[p][cg + 16 * k]);
      #pragma unroll
      for (int k = 0; k < 32; ++k) acc += dot4(whhr[k], lds4[p][64 + cg + 16 * k]);
      acc += __shfl_xor(acc, 1);
      acc += __shfl_xor(acc, 2);
      acc += __shfl_xor(acc, 4);
      acc += __shfl_xor(acc, 8);
      if (cg == 0)
        cstore1(&h0s[(s & 7) * H_DIM + row], tanhf(acc + bias) + tagctr(s));
    }

    if (wg == 0) {
      __syncthreads();  // all threads done reading lds4 for step L_SEQ before FC reuses it
      float* lred = (float*)lds4;
      if (tid < 512) {
        float4 hv = poll4(h1s + (L_SEQ & 7) * H_DIM + tid * 4, tagctr(L_SEQ));  // h1_8192
        float4 wv = ((const float4*)Wfc)[tid];
        float pz = dot4(hv, wv);
        pz += __shfl_xor(pz, 1);  pz += __shfl_xor(pz, 2);  pz += __shfl_xor(pz, 4);
        pz += __shfl_xor(pz, 8);  pz += __shfl_xor(pz, 16); pz += __shfl_xor(pz, 32);
        if ((tid & 63) == 0) lred[tid >> 6] = pz;
      }
      __syncthreads();
      if (tid == 0) {
        float z = bfc[0];
        #pragma unroll
        for (int w = 0; w < 8; ++w) z += lred[w];
        out[0] = 1.f / (1.f + expf(-z));
        __hip_atomic_store(runctr, runbase + 1, __ATOMIC_RELAXED, __HIP_MEMORY_SCOPE_AGENT);
      }
    }
  } else {
    // ---------------- layer 1: 32 rows/WG, 32 threads/row ----------------
    const int cg  = tid & 31;
    const int wgl = wg - NWG0;
    const int row = wgl * 32 + (tid >> 5);
    float4 wihr[16], whhr[16];
    {
      const float* wr = Wih1 + (size_t)row * H_DIM + (cg << 2);
      #pragma unroll
      for (int k = 0; k < 16; ++k) wihr[k] = ld4(wr + (k << 7));
      const float* wr2 = Whh1 + (size_t)row * H_DIM + (cg << 2);
      #pragma unroll
      for (int k = 0; k < 16; ++k) whhr[k] = ld4(wr2 + (k << 7));
    }
    const float bias = bih1[row] + bhh1[row];

    if (tid < 32) cstore1(&h1s[wgl * 32 + tid], 4.0f);  // h1_0 = 0, slot 0
    if (tid < 224) {
      int sl = 1 + (tid >> 5);
      cstore1(&h1s[sl * H_DIM + wgl * 32 + (tid & 31)], 0.0f);
    }
    start_barrier(slots, wg, tid, runbase + 1);

    for (int u = 2; u <= NSTEP; ++u) {   // computes h1_{u-1} from h0_{u-1}, h1_{u-2}
      const int p = u & 1;
      if (tid < 512) {
        lds4[p][tid] = poll4(h0s + ((u - 1) & 7) * H_DIM + tid * 4, tagctr(u - 1));
      } else {
        const int c = tid - 512;
        lds4[p][512 + c] = poll4(h1s + ((u - 2) & 7) * H_DIM + c * 4, tagctr(u - 2));
      }
      __syncthreads();
      float acc = 0.f;
      #pragma unroll
      for (int k = 0; k < 16; ++k) acc += dot4(wihr[k], lds4[p][cg + 32 * k]);
      #pragma unroll
      for (int k = 0; k < 16; ++k) acc += dot4(whhr[k], lds4[p][512 + cg + 32 * k]);
      acc += __shfl_xor(acc, 1);
      acc += __shfl_xor(acc, 2);
      acc += __shfl_xor(acc, 4);
      acc += __shfl_xor(acc, 8);
      acc += __shfl_xor(acc, 16);
      if (cg == 0)
        cstore1(&h1s[((u - 1) & 7) * H_DIM + row], tanhf(acc + bias) + tagctr(u - 1));
    }
  }
}

extern "C" void kernel_launch(void* const* d_in, const int* in_sizes, int n_in,
                              void* d_out, int out_size, void* d_ws, size_t ws_size,
                              hipStream_t stream) {
  const float* xx   = (const float*)d_in[0];
  const float* Wih0 = (const float*)d_in[1];
  const float* Whh0 = (const float*)d_in[2];
  const float* bih0 = (const float*)d_in[3];
  const float* bhh0 = (const float*)d_in[4];
  const float* Wih1 = (const float*)d_in[5];
  const float* Whh1 = (const float*)d_in[6];
  const float* bih1 = (const float*)d_in[7];
  const float* bhh1 = (const float*)d_in[8];
  const float* Wfc  = (const float*)d_in[9];
  const float* bfc  = (const float*)d_in[10];

  unsigned* runctr = (unsigned*)d_ws;
  unsigned* slots  = (unsigned*)((char*)d_ws + 256);
  float* h0s       = (float*)((char*)d_ws + 1024);
  float* h1s       = (float*)((char*)d_ws + 1024 + 8 * H_DIM * sizeof(float));

  rnn2_dataflow<<<dim3(NWG), dim3(TPB), 0, stream>>>(
      xx, Wih0, Whh0, bih0, bhh0, Wih1, Whh1, bih1, bhh1, Wfc, bfc,
      (float*)d_out, runctr, slots, h0s, h1s);
}

// Round 4
// 33140.906 us; speedup vs baseline: 2.4958x; 2.4958x over previous
//
#include <hip/hip_runtime.h>
#include <math.h>

#define L_SEQ 8192
#define I_DIM 256
#define H_DIM 2048
#define NWG0  64          // layer-0: 64 WGs x 32 rows (16 thr/row)
#define NWG1  128         // layer-1: 128 WGs x 16 rows (32 thr/row)
#define NWG   (NWG0 + NWG1)
#define TPB   512

// ws layout (bytes): [0] runctr | [256..1024) start-barrier slots
//                    [1024) h0 ring 8*2048 f32 | [66560) h1 ring 8*2048 f32
//
// Self-tagged dataflow (no per-step barrier): published value = h + ctr(step),
// ctr = 4 + 8*((step>>3)&1), ring depth 8, valid iff |v-ctr|<=1. 0xAA poison and
// the 0.0f invalidation marker fall outside both windows. Per run: invalidate
// all 8 ring slots for owned rows (slot 0 gets fresh tagged h_0), one start
// barrier, then pure data polling. Ring-overwrite safety:
//  - intra-layer (h0 by L0, h1 by L1): a WG at step s has validated the FULL
//    h_{s-1} => every peer published s-1 => (sequential per-WG) every peer has
//    consumed h_{s-8}. Depth-8 ring safe.
//  - cross-layer (L1 consumes h0): L0 at step s spins until one sentinel row of
//    EVERY L1 WG shows h1_{s-5} => all L1 WGs consumed h0_{s-5} (and older),
//    so overwriting h0_{s-8} is safe. Slot (s-5)&7 != s&7, so the sentinel can
//    never have been overwritten by a newer value (L1 can't pass step s).

__device__ __forceinline__ void cstore1(float* p, float v) {
  asm volatile("global_store_dword %0, %1, off sc0 sc1" :: "v"(p), "v"(v) : "memory");
}
__device__ __forceinline__ void cstoreu(unsigned* p, unsigned v) {
  asm volatile("global_store_dword %0, %1, off sc0 sc1" :: "v"(p), "v"(v) : "memory");
}
__device__ __forceinline__ float cload1(const float* p) {
  float v;
  asm volatile("global_load_dword %0, %1, off sc0 sc1\n\ts_waitcnt vmcnt(0)"
               : "=v"(v) : "v"(p) : "memory");
  return v;
}
__device__ __forceinline__ unsigned cloadu(const unsigned* p) {
  unsigned v;
  asm volatile("global_load_dword %0, %1, off sc0 sc1\n\ts_waitcnt vmcnt(0)"
               : "=v"(v) : "v"(p) : "memory");
  return v;
}
__device__ __forceinline__ float4 cload4(const float* p) {
  float4 v;
  asm volatile("global_load_dwordx4 %0, %1, off sc0 sc1\n\ts_waitcnt vmcnt(0)"
               : "=v"(v) : "v"(p) : "memory");
  return v;
}
__device__ __forceinline__ void cload4x2(const float* p0, const float* p1, float4& a, float4& b) {
  asm volatile("global_load_dwordx4 %0, %2, off sc0 sc1\n\t"
               "global_load_dwordx4 %1, %3, off sc0 sc1\n\t"
               "s_waitcnt vmcnt(0)"
               : "=&v"(a), "=&v"(b) : "v"(p0), "v"(p1) : "memory");
}
// Weight load: opaque to LLVM -> cannot be rematerialized; stays in VGPRs.
__device__ __forceinline__ float4 ld4(const float* p) {
  float4 v;
  asm volatile("global_load_dwordx4 %0, %1, off\n\ts_waitcnt vmcnt(0)"
               : "=v"(v) : "v"(p) : "memory");
  return v;
}
__device__ __forceinline__ float dot4(float4 a, float4 b) {
  return a.x * b.x + a.y * b.y + a.z * b.z + a.w * b.w;
}
__device__ __forceinline__ float tagctr(int step) {
  return 4.f + 8.f * (float)((step >> 3) & 1);
}
__device__ __forceinline__ bool ok4(float4 v, float c) {
  return __builtin_fabsf(v.x - c) <= 1.f && __builtin_fabsf(v.y - c) <= 1.f &&
         __builtin_fabsf(v.z - c) <= 1.f && __builtin_fabsf(v.w - c) <= 1.f;
}
__device__ __forceinline__ float4 poll4(const float* p, float c) {
  for (;;) {
    float4 v = cload4(p);
    if (ok4(v, c)) return make_float4(v.x - c, v.y - c, v.z - c, v.w - c);
  }
}
__device__ __forceinline__ void poll4x2(const float* p0, float c0,
                                        const float* p1, float c1,
                                        float4& a, float4& b) {
  for (;;) {
    float4 u, v;
    cload4x2(p0, p1, u, v);
    if (ok4(u, c0) && ok4(v, c1)) {
      a = make_float4(u.x - c0, u.y - c0, u.z - c0, u.w - c0);
      b = make_float4(v.x - c1, v.y - c1, v.z - c1, v.w - c1);
      return;
    }
  }
}

__device__ __forceinline__ void start_barrier(unsigned* slots, int wg, int tid, unsigned value) {
  __syncthreads();  // drains vmcnt(0): this WG's init stores are at the coherence point
  if (tid == 0) cstoreu(&slots[wg], value);
  if (tid < NWG) {
    while ((int)(cloadu(&slots[tid]) - value) < 0) __builtin_amdgcn_s_sleep(1);
  }
  __syncthreads();
}

__global__ __launch_bounds__(TPB, 2)
void rnn2_dataflow(const float* __restrict__ x,
                   const float* __restrict__ Wih0, const float* __restrict__ Whh0,
                   const float* __restrict__ bih0, const float* __restrict__ bhh0,
                   const float* __restrict__ Wih1, const float* __restrict__ Whh1,
                   const float* __restrict__ bih1, const float* __restrict__ bhh1,
                   const float* __restrict__ Wfc,  const float* __restrict__ bfc,
                   float* __restrict__ out,
                   unsigned* __restrict__ runctr, unsigned* __restrict__ slots,
                   float* __restrict__ h0s, float* __restrict__ h1s)
{
  const int wg  = blockIdx.x;
  const int tid = threadIdx.x;
  __shared__ float4 lds4[2][1024];

  const unsigned runbase = cloadu(runctr);

  if (wg < NWG0) {
    // ---------------- layer 0: 32 rows/WG, 16 threads/row ----------------
    const int cg  = tid & 15;
    const int row = wg * 32 + (tid >> 4);
    float4 wihr[4], whhr[32];
    {
      const float* wr = Wih0 + (size_t)row * I_DIM + (cg << 2);
      #pragma unroll
      for (int k = 0; k < 4; ++k) wihr[k] = ld4(wr + (k << 6));
      const float* wr2 = Whh0 + (size_t)row * H_DIM + (cg << 2);
      #pragma unroll
      for (int k = 0; k < 32; ++k) whhr[k] = ld4(wr2 + (k << 6));
    }
    const float bias = bih0[row] + bhh0[row];

    // init: slot 0 = tagged h0_0 = 0; slots 1..7 invalidated, owned rows only
    if (tid < 32) cstore1(&h0s[wg * 32 + tid], 4.0f);
    if (tid < 224) {
      int sl = 1 + (tid >> 5);
      cstore1(&h0s[sl * H_DIM + wg * 32 + (tid & 31)], 0.0f);
    }
    start_barrier(slots, wg, tid, runbase + 1);

    for (int s = 1; s <= L_SEQ; ++s) {
      const int p = s & 1;
      if (s >= 9 && tid < NWG1) {
        // sound cross-layer throttle: every L1 WG must have published h1_{s-5}
        const float c = tagctr(s - 5);
        const float* tp = h1s + ((s - 5) & 7) * H_DIM + (tid << 4);  // row 16*tid
        while (__builtin_fabsf(cload1(tp) - c) > 1.f) {}
      }
      float4 xv;
      if (tid < 64) xv = ((const float4*)x)[(size_t)(s - 1) * 64 + tid];
      lds4[p][64 + tid] = poll4(h0s + ((s - 1) & 7) * H_DIM + (tid << 2), tagctr(s - 1));
      if (tid < 64) lds4[p][tid] = xv;
      __syncthreads();
      float acc = 0.f;
      #pragma unroll
      for (int k = 0; k < 4; ++k)  acc += dot4(wihr[k], lds4[p][cg + 16 * k]);
      #pragma unroll
      for (int k = 0; k < 32; ++k) acc += dot4(whhr[k], lds4[p][64 + cg + 16 * k]);
      acc += __shfl_xor(acc, 1);
      acc += __shfl_xor(acc, 2);
      acc += __shfl_xor(acc, 4);
      acc += __shfl_xor(acc, 8);
      if (cg == 0)
        cstore1(&h0s[(s & 7) * H_DIM + row], tanhf(acc + bias) + tagctr(s));
    }

    if (wg == 0) {
      // final FC: sigmoid(h1_8192 . Wfc + bfc); step 8192 -> slot 0, ctr 4
      float4 hv = poll4(h1s + (tid << 2), tagctr(L_SEQ));
      float4 wv = ((const float4*)Wfc)[tid];
      float pz = dot4(hv, wv);
      pz += __shfl_xor(pz, 1);  pz += __shfl_xor(pz, 2);  pz += __shfl_xor(pz, 4);
      pz += __shfl_xor(pz, 8);  pz += __shfl_xor(pz, 16); pz += __shfl_xor(pz, 32);
      float* lred = (float*)&lds4[0][0];
      if ((tid & 63) == 0) lred[tid >> 6] = pz;
      __syncthreads();
      if (tid == 0) {
        float z = bfc[0];
        #pragma unroll
        for (int w = 0; w < TPB / 64; ++w) z += lred[w];
        out[0] = 1.f / (1.f + expf(-z));
        cstoreu(runctr, runbase + 1);
      }
    }
  } else {
    // ---------------- layer 1: 16 rows/WG, 32 threads/row ----------------
    const int cg  = tid & 31;
    const int wgl = wg - NWG0;
    const int row = wgl * 16 + (tid >> 5);
    float4 wihr[16], whhr[16];
    {
      const float* wr = Wih1 + (size_t)row * H_DIM + (cg << 2);
      #pragma unroll
      for (int k = 0; k < 16; ++k) wihr[k] = ld4(wr + (k << 7));
      const float* wr2 = Whh1 + (size_t)row * H_DIM + (cg << 2);
      #pragma unroll
      for (int k = 0; k < 16; ++k) whhr[k] = ld4(wr2 + (k << 7));
    }
    const float bias = bih1[row] + bhh1[row];

    if (tid < 16) cstore1(&h1s[wgl * 16 + tid], 4.0f);  // h1_0 = 0, slot 0
    if (tid < 112) {
      int sl = 1 + (tid >> 4);
      cstore1(&h1s[sl * H_DIM + wgl * 16 + (tid & 15)], 0.0f);
    }
    start_barrier(slots, wg, tid, runbase + 1);

    for (int t = 1; t <= L_SEQ; ++t) {  // h1_t = tanh(Wih1 h0_t + Whh1 h1_{t-1} + b)
      const int p = t & 1;
      float4 a, b;
      poll4x2(h0s + (t & 7) * H_DIM + (tid << 2), tagctr(t),
              h1s + ((t - 1) & 7) * H_DIM + (tid << 2), tagctr(t - 1), a, b);
      lds4[p][tid] = a;
      lds4[p][512 + tid] = b;
      __syncthreads();
      float acc = 0.f;
      #pragma unroll
      for (int k = 0; k < 16; ++k) acc += dot4(wihr[k], lds4[p][cg + 32 * k]);
      #pragma unroll
      for (int k = 0; k < 16; ++k) acc += dot4(whhr[k], lds4[p][512 + cg + 32 * k]);
      acc += __shfl_xor(acc, 1);
      acc += __shfl_xor(acc, 2);
      acc += __shfl_xor(acc, 4);
      acc += __shfl_xor(acc, 8);
      acc += __shfl_xor(acc, 16);
      if (cg == 0)
        cstore1(&h1s[(t & 7) * H_DIM + row], tanhf(acc + bias) + tagctr(t));
    }
  }
}

extern "C" void kernel_launch(void* const* d_in, const int* in_sizes, int n_in,
                              void* d_out, int out_size, void* d_ws, size_t ws_size,
                              hipStream_t stream) {
  const float* xx   = (const float*)d_in[0];
  const float* Wih0 = (const float*)d_in[1];
  const float* Whh0 = (const float*)d_in[2];
  const float* bih0 = (const float*)d_in[3];
  const float* bhh0 = (const float*)d_in[4];
  const float* Wih1 = (const float*)d_in[5];
  const float* Whh1 = (const float*)d_in[6];
  const float* bih1 = (const float*)d_in[7];
  const float* bhh1 = (const float*)d_in[8];
  const float* Wfc  = (const float*)d_in[9];
  const float* bfc  = (const float*)d_in[10];

  unsigned* runctr = (unsigned*)d_ws;
  unsigned* slots  = (unsigned*)((char*)d_ws + 256);
  float* h0s       = (float*)((char*)d_ws + 1024);
  float* h1s       = (float*)((char*)d_ws + 1024 + 8 * H_DIM * sizeof(float));

  rnn2_dataflow<<<dim3(NWG), dim3(TPB), 0, stream>>>(
      xx, Wih0, Whh0, bih0, bhh0, Wih1, Whh1, bih1, bhh1, Wfc, bfc,
      (float*)d_out, runctr, slots, h0s, h1s);
}